// Round 1
// baseline (514.417 us; speedup 1.0000x reference)
//
#include <hip/hip_runtime.h>

// Problem constants
#define BB   2
#define LL   2048
#define DM   768
#define HH   12
#define FT   16
#define HD   64
#define DEXP 273      // 1 + 16 + 256
#define CH   128      // chunk length
#define NC   16       // chunks per sequence (LL/CH)
#define NBH  24       // BB*HH
#define NBLK 384      // NBH*NC
#define C2f  0.17677669529663687f   // 1/(4*sqrt(2))

// ---------------- K1/K5: Y[M][N] = X[M][K] @ W[N][K]^T (fp32, 64x64 tile) ----------------
__global__ __launch_bounds__(256) void gemm_xwt(
    const float* __restrict__ X, int ldx,
    const float* __restrict__ W, int ldw,
    float* __restrict__ Y, int ldy,
    int K) {
  __shared__ float As[16][68];   // [k][m], pad 68 (16B-aligned rows)
  __shared__ float Bs[16][68];   // [k][n]
  const int bm = blockIdx.y * 64, bn = blockIdx.x * 64;
  const int tid = threadIdx.x;
  const int tx = tid & 15, ty = tid >> 4;
  float acc[4][4] = {};
  for (int k0 = 0; k0 < K; k0 += 16) {
    const int c = tid & 15, r = tid >> 4;
#pragma unroll
    for (int i = 0; i < 4; i++)
      As[c][r + 16 * i] = X[(size_t)(bm + r + 16 * i) * ldx + k0 + c];
#pragma unroll
    for (int i = 0; i < 4; i++)
      Bs[c][r + 16 * i] = W[(size_t)(bn + r + 16 * i) * ldw + k0 + c];
    __syncthreads();
#pragma unroll
    for (int kk = 0; kk < 16; kk++) {
      float a_[4], b_[4];
      *(float4*)a_ = *(const float4*)&As[kk][ty * 4];
      *(float4*)b_ = *(const float4*)&Bs[kk][tx * 4];
#pragma unroll
      for (int i = 0; i < 4; i++)
#pragma unroll
        for (int j = 0; j < 4; j++) acc[i][j] += a_[i] * b_[j];
    }
    __syncthreads();
  }
#pragma unroll
  for (int i = 0; i < 4; i++) {
    float4 o;
    o.x = acc[i][0]; o.y = acc[i][1]; o.z = acc[i][2]; o.w = acc[i][3];
    *(float4*)&Y[(size_t)(bm + ty * 4 + i) * ldy + bn + tx * 4] = o;
  }
}

// ---------------- K2: per-chunk state sums ----------------
// csS[blk][f][e] = sum_{m in chunk} phi_k[m][f] * v[m][e]   (273x64)
// csk[blk][f]    = sum_{m in chunk} phi_k[m][f]             (273)
template <int FG>
__device__ __forceinline__ void chunk_loop(float (&acc)[69],
                                           const float (*kk)[16],
                                           const float (*vv)[64], int e) {
  for (int m = 0; m < CH; m++) {
    float kr[16];
#pragma unroll
    for (int i = 0; i < 16; i++) kr[i] = kk[m][i];
    const float vr = vv[m][e];
    float kv[16], p[16];
#pragma unroll
    for (int i = 0; i < 16; i++) kv[i] = kr[i] * vr;
#pragma unroll
    for (int i = 0; i < 16; i++) p[i] = kr[i] * C2f;
#pragma unroll
    for (int i = 0; i < 69; i++) {
      const int f = FG + 4 * i;
      if (f >= DEXP) break;
      if (f == 0)
        acc[i] += vr;                       // phi = 1
      else if (f <= 16)
        acc[i] += 0.5f * kv[f - 1];         // phi = k/2
      else
        acc[i] += p[(f - 17) >> 4] * kv[(f - 17) & 15];  // phi = ki*kj*C2
    }
  }
}

__global__ __launch_bounds__(256) void chunk_sum_kernel(
    const float* __restrict__ qkv, float* __restrict__ csS,
    float* __restrict__ csk) {
  const int blk = blockIdx.x;
  const int bh = blk >> 4, c = blk & 15;
  const int b = bh / HH, h = bh % HH;
  __shared__ float kk[CH][16];
  __shared__ float vv[CH][64];
  const float* base = qkv + (size_t)(b * LL + c * CH) * 1152;
  for (int idx = threadIdx.x; idx < CH * 16; idx += 256) {
    int m = idx >> 4, i = idx & 15;
    kk[m][i] = base[(size_t)m * 1152 + 192 + h * 16 + i];
  }
  for (int idx = threadIdx.x; idx < CH * 64; idx += 256) {
    int m = idx >> 6, e2 = idx & 63;
    vv[m][e2] = base[(size_t)m * 1152 + 384 + h * 64 + e2];
  }
  __syncthreads();
  const int e = threadIdx.x & 63, fg = threadIdx.x >> 6;
  float acc[69];
#pragma unroll
  for (int i = 0; i < 69; i++) acc[i] = 0.0f;
  switch (fg) {
    case 0: chunk_loop<0>(acc, kk, vv, e); break;
    case 1: chunk_loop<1>(acc, kk, vv, e); break;
    case 2: chunk_loop<2>(acc, kk, vv, e); break;
    default: chunk_loop<3>(acc, kk, vv, e); break;
  }
  float* S = csS + (size_t)blk * DEXP * 64;
#pragma unroll
  for (int i = 0; i < 69; i++) {
    int f = fg + 4 * i;
    if (f < DEXP) S[(size_t)f * 64 + e] = acc[i];
  }
  // k feature sums
  for (int f = threadIdx.x; f < DEXP; f += 256) {
    float s = 0.0f;
    if (f == 0) {
      s = (float)CH;
    } else if (f <= 16) {
      for (int m = 0; m < CH; m++) s += kk[m][f - 1];
      s *= 0.5f;
    } else {
      int idx = f - 17, ia = idx >> 4, ib = idx & 15;
      for (int m = 0; m < CH; m++) s += kk[m][ia] * kk[m][ib];
      s *= C2f;
    }
    csk[(size_t)blk * DEXP + f] = s;
  }
}

// ---------------- K3: across-chunk scan: G[c] = (excl prefix)[c] + total ----------------
__global__ __launch_bounds__(256) void prefix_kernel(float* __restrict__ csS,
                                                     float* __restrict__ csk) {
  const int gid = blockIdx.x * 256 + threadIdx.x;
  const int totS = NBH * DEXP * 64;  // 419328
  if (gid < totS) {
    const int bh = gid / (DEXP * 64);
    const int idx = gid % (DEXP * 64);
    float r[NC];
    float tot = 0.0f;
#pragma unroll
    for (int c = 0; c < NC; c++) {
      r[c] = csS[(size_t)(bh * NC + c) * DEXP * 64 + idx];
      tot += r[c];
    }
    float run = 0.0f;
#pragma unroll
    for (int c = 0; c < NC; c++) {
      csS[(size_t)(bh * NC + c) * DEXP * 64 + idx] = run + tot;
      run += r[c];
    }
  } else {
    const int g2 = gid - totS;
    if (g2 < NBH * DEXP) {
      const int bh = g2 / DEXP;
      const int f = g2 % DEXP;
      float r[NC];
      float tot = 0.0f;
#pragma unroll
      for (int c = 0; c < NC; c++) {
        r[c] = csk[(size_t)(bh * NC + c) * DEXP + f];
        tot += r[c];
      }
      float run = 0.0f;
#pragma unroll
      for (int c = 0; c < NC; c++) {
        csk[(size_t)(bh * NC + c) * DEXP + f] = run + tot;
        run += r[c];
      }
    }
  }
}

// ---------------- K4: per-chunk output ----------------
// y_t = [ phi(q_t)^T G  +  sum_{m<=t in chunk} a_tm v_m ] / d_t
// a_tm = 1 + s/4 + s^2/32,  s = q_t . k_m (16 dims)
__global__ __launch_bounds__(256) void out_kernel(const float* __restrict__ qkv,
                                                  const float* __restrict__ csS,
                                                  const float* __restrict__ csk,
                                                  float* __restrict__ att) {
  const int blk = blockIdx.x;
  const int bh = blk >> 4, c = blk & 15;
  const int b = bh / HH, h = bh % HH;
  __shared__ float ks[CH][17];
  __shared__ float vs[CH][64];
  __shared__ float gk[DEXP];
  __shared__ float qst[32][17];
  __shared__ float a_s[32][129];
  __shared__ float zl[32];
  const float* base = qkv + (size_t)(b * LL + c * CH) * 1152;
  const int tid = threadIdx.x;
  for (int idx = tid; idx < CH * 16; idx += 256) {
    int m = idx >> 4, i = idx & 15;
    ks[m][i] = base[(size_t)m * 1152 + 192 + h * 16 + i];
  }
  for (int idx = tid; idx < CH * 64; idx += 256) {
    int m = idx >> 6, e2 = idx & 63;
    vs[m][e2] = base[(size_t)m * 1152 + 384 + h * 64 + e2];
  }
  for (int f = tid; f < DEXP; f += 256) gk[f] = csk[(size_t)blk * DEXP + f];
  __syncthreads();
  const float* Gc = csS + (size_t)blk * DEXP * 64;
  const int e4 = (tid & 15) * 4, tq = tid >> 4;  // thread: e4..e4+3, rows tq & tq+16

  for (int tt = 0; tt < 4; tt++) {
    const int t0 = tt * 32;
    // load q tile
    for (int idx = tid; idx < 32 * 16; idx += 256) {
      int t = idx >> 4, i = idx & 15;
      qst[t][i] = base[(size_t)(t0 + t) * 1152 + h * 16 + i];
    }
    __syncthreads();
    // scores (causal-masked within chunk)
    for (int idx = tid; idx < 32 * CH; idx += 256) {
      int t = idx >> 7, m = idx & 127;
      float s = 0.0f;
#pragma unroll
      for (int i = 0; i < 16; i++) s += qst[t][i] * ks[m][i];
      a_s[t][m] = (m <= t0 + t) ? fmaf(s, fmaf(s, 0.03125f, 0.25f), 1.0f) : 0.0f;
    }
    __syncthreads();
    // denominators
    if (tid < 32) {
      const int t = tid;
      float d = 0.0f;
      for (int m = 0; m < CH; m++) d += a_s[t][m];
      float qr[16];
#pragma unroll
      for (int i = 0; i < 16; i++) qr[i] = qst[t][i];
      d += gk[0];
#pragma unroll
      for (int i = 0; i < 16; i++) d += 0.5f * qr[i] * gk[1 + i];
#pragma unroll
      for (int i = 0; i < 16; i++) {
        const float qc = qr[i] * C2f;
#pragma unroll
        for (int j = 0; j < 16; j++) d += qc * qr[j] * gk[17 + i * 16 + j];
      }
      zl[t] = 1.0f / d;
    }
    __syncthreads();
    // state matvec + intra-chunk
    float ac0[4] = {0, 0, 0, 0}, ac1[4] = {0, 0, 0, 0};
    {
      float g[4];
      *(float4*)g = *(const float4*)(Gc + e4);  // f = 0
#pragma unroll
      for (int j = 0; j < 4; j++) { ac0[j] += g[j]; ac1[j] += g[j]; }
    }
#pragma unroll
    for (int i2 = 0; i2 < 16; i2++) {
      float g[4];
      *(float4*)g = *(const float4*)(Gc + (size_t)(1 + i2) * 64 + e4);
      const float qa = qst[tq][i2] * 0.5f, qb = qst[tq + 16][i2] * 0.5f;
#pragma unroll
      for (int j = 0; j < 4; j++) { ac0[j] += qa * g[j]; ac1[j] += qb * g[j]; }
    }
    for (int i2 = 0; i2 < 16; i2++) {
      const float qa = qst[tq][i2] * C2f, qb = qst[tq + 16][i2] * C2f;
#pragma unroll
      for (int j2 = 0; j2 < 16; j2++) {
        float g[4];
        *(float4*)g = *(const float4*)(Gc + (size_t)(17 + i2 * 16 + j2) * 64 + e4);
        const float pa = qa * qst[tq][j2], pb = qb * qst[tq + 16][j2];
#pragma unroll
        for (int j = 0; j < 4; j++) { ac0[j] += pa * g[j]; ac1[j] += pb * g[j]; }
      }
    }
    for (int m = 0; m < CH; m++) {
      float v4[4];
      *(float4*)v4 = *(const float4*)&vs[m][e4];
      const float a0 = a_s[tq][m], a1 = a_s[tq + 16][m];
#pragma unroll
      for (int j = 0; j < 4; j++) { ac0[j] += a0 * v4[j]; ac1[j] += a1 * v4[j]; }
    }
    const float z0 = zl[tq], z1 = zl[tq + 16];
    float* o0 = att + (size_t)(b * LL + c * CH + t0 + tq) * DM + h * 64 + e4;
    float* o1 = att + (size_t)(b * LL + c * CH + t0 + tq + 16) * DM + h * 64 + e4;
    float4 w0, w1;
    w0.x = ac0[0] * z0; w0.y = ac0[1] * z0; w0.z = ac0[2] * z0; w0.w = ac0[3] * z0;
    w1.x = ac1[0] * z1; w1.y = ac1[1] * z1; w1.z = ac1[2] * z1; w1.w = ac1[3] * z1;
    *(float4*)o0 = w0;
    *(float4*)o1 = w1;
    __syncthreads();
  }
}

extern "C" void kernel_launch(void* const* d_in, const int* in_sizes, int n_in,
                              void* d_out, int out_size, void* d_ws, size_t ws_size,
                              hipStream_t stream) {
  const float* hs = (const float*)d_in[0];
  const float* Wq = (const float*)d_in[1];
  const float* Wk = (const float*)d_in[2];
  const float* Wv = (const float*)d_in[3];
  const float* Wo = (const float*)d_in[4];
  float* out = (float*)d_out;
  char* ws = (char*)d_ws;
  // workspace layout (bytes)
  float* qkv = (float*)(ws);                     // 4096*1152*4 = 18874368
  float* att = (float*)(ws + 18874368);          // 4096*768*4  = 12582912
  float* csS = (float*)(ws + 31457280);          // 384*273*64*4 = 26836992
  float* csk = (float*)(ws + 58294272);          // 384*273*4   = 419328
  const dim3 thr(256);
  const int M = BB * LL;  // 4096
  // QKV projections into [M][1152]: cols 0..191 q, 192..383 k, 384..1151 v
  gemm_xwt<<<dim3(192 / 64, M / 64), thr, 0, stream>>>(hs, DM, Wq, DM, qkv, 1152, DM);
  gemm_xwt<<<dim3(192 / 64, M / 64), thr, 0, stream>>>(hs, DM, Wk, DM, qkv + 192, 1152, DM);
  gemm_xwt<<<dim3(768 / 64, M / 64), thr, 0, stream>>>(hs, DM, Wv, DM, qkv + 384, 1152, DM);
  chunk_sum_kernel<<<NBLK, thr, 0, stream>>>(qkv, csS, csk);
  {
    const int tot = NBH * DEXP * 64 + NBH * DEXP;
    prefix_kernel<<<(tot + 255) / 256, thr, 0, stream>>>(csS, csk);
  }
  out_kernel<<<NBLK, thr, 0, stream>>>(qkv, csS, csk, att);
  gemm_xwt<<<dim3(768 / 64, M / 64), thr, 0, stream>>>(att, DM, Wo, DM, out, DM, DM);
}

// Round 2
// 436.257 us; speedup vs baseline: 1.1792x; 1.1792x over previous
//
#include <hip/hip_runtime.h>

// Problem constants
#define BB   2
#define LL   2048
#define DM   768
#define HH   12
#define FT   16
#define HD   64
#define DEXP 273      // 1 + 16 + 256
#define CH   128      // chunk length
#define NC   16       // chunks per sequence (LL/CH)
#define NBH  24       // BB*HH
#define NBLK 384      // NBH*NC
#define C2f  0.17677669529663687f   // 1/(4*sqrt(2))

// ---------------- GEMM: Y[M][N] = X[M][768] @ Wsel[N][768]^T, 128x128 tile, 8x8/thread ----
// Weight row n selected from {W0 (n<n1), W1 (n<n2), W2} to fuse Q/K/V into one launch.
__global__ __launch_bounds__(256, 2) void gemm128(
    const float* __restrict__ X,
    const float* __restrict__ W0, const float* __restrict__ W1,
    const float* __restrict__ W2, int n1, int n2,
    float* __restrict__ Y, int ldy) {
  __shared__ float As[16][132];
  __shared__ float Bs[16][132];
  const int bm = blockIdx.y * 128, bn = blockIdx.x * 128;
  const int tid = threadIdx.x;
  const int rr = tid >> 2, kc4 = (tid & 3) * 4;
  const float* a0 = X + (size_t)(bm + rr) * 768 + kc4;
  const float* a1 = a0 + (size_t)64 * 768;
  const int nr0 = bn + rr, nr1 = bn + rr + 64;
  const float* b0 = (nr0 < n1 ? W0 + (size_t)nr0 * 768
                   : nr0 < n2 ? W1 + (size_t)(nr0 - n1) * 768
                              : W2 + (size_t)(nr0 - n2) * 768) + kc4;
  const float* b1 = (nr1 < n1 ? W0 + (size_t)nr1 * 768
                   : nr1 < n2 ? W1 + (size_t)(nr1 - n1) * 768
                              : W2 + (size_t)(nr1 - n2) * 768) + kc4;
  const int tx = tid & 15, ty = tid >> 4;
  float acc[8][8] = {};
  for (int k0 = 0; k0 < 768; k0 += 16) {
    const float4 va0 = *(const float4*)(a0 + k0);
    const float4 va1 = *(const float4*)(a1 + k0);
    const float4 vb0 = *(const float4*)(b0 + k0);
    const float4 vb1 = *(const float4*)(b1 + k0);
    __syncthreads();
    As[kc4 + 0][rr] = va0.x; As[kc4 + 1][rr] = va0.y;
    As[kc4 + 2][rr] = va0.z; As[kc4 + 3][rr] = va0.w;
    As[kc4 + 0][rr + 64] = va1.x; As[kc4 + 1][rr + 64] = va1.y;
    As[kc4 + 2][rr + 64] = va1.z; As[kc4 + 3][rr + 64] = va1.w;
    Bs[kc4 + 0][rr] = vb0.x; Bs[kc4 + 1][rr] = vb0.y;
    Bs[kc4 + 2][rr] = vb0.z; Bs[kc4 + 3][rr] = vb0.w;
    Bs[kc4 + 0][rr + 64] = vb1.x; Bs[kc4 + 1][rr + 64] = vb1.y;
    Bs[kc4 + 2][rr + 64] = vb1.z; Bs[kc4 + 3][rr + 64] = vb1.w;
    __syncthreads();
#pragma unroll
    for (int kk = 0; kk < 16; kk++) {
      float a_[8], b_[8];
      *(float4*)(a_) = *(const float4*)&As[kk][ty * 4];
      *(float4*)(a_ + 4) = *(const float4*)&As[kk][ty * 4 + 64];
      *(float4*)(b_) = *(const float4*)&Bs[kk][tx * 4];
      *(float4*)(b_ + 4) = *(const float4*)&Bs[kk][tx * 4 + 64];
#pragma unroll
      for (int i = 0; i < 8; i++)
#pragma unroll
        for (int j = 0; j < 8; j++) acc[i][j] += a_[i] * b_[j];
    }
  }
#pragma unroll
  for (int ih = 0; ih < 2; ih++)
#pragma unroll
    for (int i = 0; i < 4; i++) {
      const int row = bm + ih * 64 + ty * 4 + i;
      float* yp = Y + (size_t)row * ldy + bn + tx * 4;
      float4 o0, o1;
      o0.x = acc[ih * 4 + i][0]; o0.y = acc[ih * 4 + i][1];
      o0.z = acc[ih * 4 + i][2]; o0.w = acc[ih * 4 + i][3];
      o1.x = acc[ih * 4 + i][4]; o1.y = acc[ih * 4 + i][5];
      o1.z = acc[ih * 4 + i][6]; o1.w = acc[ih * 4 + i][7];
      *(float4*)yp = o0;
      *(float4*)(yp + 64) = o1;
    }
}

// ---------------- K2: per-chunk state sums ----------------
template <int FG>
__device__ __forceinline__ void chunk_loop(float (&acc)[69],
                                           const float (*kk)[16],
                                           const float (*vv)[64], int e) {
  for (int m = 0; m < CH; m++) {
    float kr[16];
#pragma unroll
    for (int i = 0; i < 16; i++) kr[i] = kk[m][i];
    const float vr = vv[m][e];
    float kv[16], p[16];
#pragma unroll
    for (int i = 0; i < 16; i++) kv[i] = kr[i] * vr;
#pragma unroll
    for (int i = 0; i < 16; i++) p[i] = kr[i] * C2f;
#pragma unroll
    for (int i = 0; i < 69; i++) {
      const int f = FG + 4 * i;
      if (f >= DEXP) break;
      if (f == 0)
        acc[i] += vr;
      else if (f <= 16)
        acc[i] += 0.5f * kv[f - 1];
      else
        acc[i] += p[(f - 17) >> 4] * kv[(f - 17) & 15];
    }
  }
}

__global__ __launch_bounds__(256) void chunk_sum_kernel(
    const float* __restrict__ qkv, float* __restrict__ csS,
    float* __restrict__ csk) {
  const int blk = blockIdx.x;
  const int bh = blk >> 4, c = blk & 15;
  const int b = bh / HH, h = bh % HH;
  __shared__ float kk[CH][16];
  __shared__ float vv[CH][64];
  const float* base = qkv + (size_t)(b * LL + c * CH) * 1152;
  for (int idx = threadIdx.x; idx < CH * 16; idx += 256) {
    int m = idx >> 4, i = idx & 15;
    kk[m][i] = base[(size_t)m * 1152 + 192 + h * 16 + i];
  }
  for (int idx = threadIdx.x; idx < CH * 64; idx += 256) {
    int m = idx >> 6, e2 = idx & 63;
    vv[m][e2] = base[(size_t)m * 1152 + 384 + h * 64 + e2];
  }
  __syncthreads();
  const int e = threadIdx.x & 63, fg = threadIdx.x >> 6;
  float acc[69];
#pragma unroll
  for (int i = 0; i < 69; i++) acc[i] = 0.0f;
  switch (fg) {
    case 0: chunk_loop<0>(acc, kk, vv, e); break;
    case 1: chunk_loop<1>(acc, kk, vv, e); break;
    case 2: chunk_loop<2>(acc, kk, vv, e); break;
    default: chunk_loop<3>(acc, kk, vv, e); break;
  }
  float* S = csS + (size_t)blk * DEXP * 64;
#pragma unroll
  for (int i = 0; i < 69; i++) {
    int f = fg + 4 * i;
    if (f < DEXP) S[(size_t)f * 64 + e] = acc[i];
  }
  for (int f = threadIdx.x; f < DEXP; f += 256) {
    float s = 0.0f;
    if (f == 0) {
      s = (float)CH;
    } else if (f <= 16) {
      for (int m = 0; m < CH; m++) s += kk[m][f - 1];
      s *= 0.5f;
    } else {
      int idx = f - 17, ia = idx >> 4, ib = idx & 15;
      for (int m = 0; m < CH; m++) s += kk[m][ia] * kk[m][ib];
      s *= C2f;
    }
    csk[(size_t)blk * DEXP + f] = s;
  }
}

// ---------------- K3: across-chunk scan: G[c] = (excl prefix)[c] + total ----------------
__global__ __launch_bounds__(256) void prefix_kernel(float* __restrict__ csS,
                                                     float* __restrict__ csk) {
  const int gid = blockIdx.x * 256 + threadIdx.x;
  const int totS = NBH * DEXP * 64;
  if (gid < totS) {
    const int bh = gid / (DEXP * 64);
    const int idx = gid % (DEXP * 64);
    float r[NC];
    float tot = 0.0f;
#pragma unroll
    for (int c = 0; c < NC; c++) {
      r[c] = csS[(size_t)(bh * NC + c) * DEXP * 64 + idx];
      tot += r[c];
    }
    float run = 0.0f;
#pragma unroll
    for (int c = 0; c < NC; c++) {
      csS[(size_t)(bh * NC + c) * DEXP * 64 + idx] = run + tot;
      run += r[c];
    }
  } else {
    const int g2 = gid - totS;
    if (g2 < NBH * DEXP) {
      const int bh = g2 / DEXP;
      const int f = g2 % DEXP;
      float r[NC];
      float tot = 0.0f;
#pragma unroll
      for (int c = 0; c < NC; c++) {
        r[c] = csk[(size_t)(bh * NC + c) * DEXP + f];
        tot += r[c];
      }
      float run = 0.0f;
#pragma unroll
      for (int c = 0; c < NC; c++) {
        csk[(size_t)(bh * NC + c) * DEXP + f] = run + tot;
        run += r[c];
      }
    }
  }
}

// ---------------- K4a: y_state = phi(q) @ G, d_state = phi(q).gk ----------------
// grid (NBLK, 4): one 32-row tile per block. LDS ~2.3KB -> high occupancy.
__global__ __launch_bounds__(256) void state_kernel(
    const float* __restrict__ qkv, const float* __restrict__ csS,
    const float* __restrict__ csk, float* __restrict__ att,
    float* __restrict__ dst) {
  const int blk = blockIdx.x, tt = blockIdx.y;
  const int bh = blk >> 4, c = blk & 15;
  const int b = bh / HH, h = bh % HH;
  const int t0 = tt * 32;
  __shared__ float qst[32][17];
  __shared__ float gk[DEXP];
  const float* base = qkv + (size_t)(b * LL + c * CH) * 1152 + h * 16;
  const int tid = threadIdx.x;
  for (int idx = tid; idx < 32 * 16; idx += 256) {
    int t = idx >> 4, i = idx & 15;
    qst[t][i] = base[(size_t)(t0 + t) * 1152 + i];
  }
  for (int f = tid; f < DEXP; f += 256) gk[f] = csk[(size_t)blk * DEXP + f];
  __syncthreads();
  const float* Gc = csS + (size_t)blk * DEXP * 64;
  const int e4 = (tid & 15) * 4, tq = tid >> 4;
  float q0[16], q1[16];
#pragma unroll
  for (int i = 0; i < 16; i++) { q0[i] = qst[tq][i]; q1[i] = qst[tq + 16][i]; }
  float ac0[4], ac1[4];
  {
    float g[4];
    *(float4*)g = *(const float4*)(Gc + e4);  // f = 0 (phi = 1)
#pragma unroll
    for (int j = 0; j < 4; j++) { ac0[j] = g[j]; ac1[j] = g[j]; }
  }
#pragma unroll
  for (int i2 = 0; i2 < 16; i2++) {
    float g[4];
    *(float4*)g = *(const float4*)(Gc + (size_t)(1 + i2) * 64 + e4);
    const float qa = q0[i2] * 0.5f, qb = q1[i2] * 0.5f;
#pragma unroll
    for (int j = 0; j < 4; j++) { ac0[j] += qa * g[j]; ac1[j] += qb * g[j]; }
  }
  for (int i2 = 0; i2 < 16; i2++) {
    const float qa = q0[i2] * C2f, qb = q1[i2] * C2f;
    const float* Gr = Gc + (size_t)(17 + i2 * 16) * 64 + e4;
#pragma unroll
    for (int j2 = 0; j2 < 16; j2++) {
      float g[4];
      *(float4*)g = *(const float4*)(Gr + (size_t)j2 * 64);
      const float pa = qa * q0[j2], pb = qb * q1[j2];
#pragma unroll
      for (int j = 0; j < 4; j++) { ac0[j] += pa * g[j]; ac1[j] += pb * g[j]; }
    }
  }
  const size_t row0 = (size_t)(b * LL + c * CH + t0 + tq);
  float4 w0, w1;
  w0.x = ac0[0]; w0.y = ac0[1]; w0.z = ac0[2]; w0.w = ac0[3];
  w1.x = ac1[0]; w1.y = ac1[1]; w1.z = ac1[2]; w1.w = ac1[3];
  *(float4*)&att[row0 * DM + h * 64 + e4] = w0;
  *(float4*)&att[(row0 + 16) * DM + h * 64 + e4] = w1;
  if (tid < 32) {
    const int t = tid;
    float qr[16];
#pragma unroll
    for (int i = 0; i < 16; i++) qr[i] = qst[t][i];
    float d = gk[0];
#pragma unroll
    for (int i = 0; i < 16; i++) d += 0.5f * qr[i] * gk[1 + i];
#pragma unroll
    for (int i = 0; i < 16; i++) {
      const float qc = qr[i] * C2f;
#pragma unroll
      for (int j = 0; j < 16; j++) d += qc * qr[j] * gk[17 + i * 16 + j];
    }
    dst[(size_t)bh * LL + c * CH + t0 + t] = d;
  }
}

// ---------------- K4b: intra-chunk causal part + final scaling ----------------
// grid (NBLK, 4, 2): 32-row tile x 32-col half. att updated in place.
__global__ __launch_bounds__(256) void intra_kernel(
    const float* __restrict__ qkv, const float* __restrict__ dst,
    float* __restrict__ att) {
  const int blk = blockIdx.x, tt = blockIdx.y, ez = blockIdx.z;
  const int bh = blk >> 4, c = blk & 15;
  const int b = bh / HH, h = bh % HH;
  const int t0 = tt * 32, Mn = t0 + 32;
  const int E0 = ez * 32;
  __shared__ float ks[CH][17];
  __shared__ float vs[CH][32];
  __shared__ float qst[32][17];
  __shared__ float a_s[32][129];
  __shared__ float zl[32];
  const float* base = qkv + (size_t)(b * LL + c * CH) * 1152;
  const int tid = threadIdx.x;
  for (int idx = tid; idx < Mn * 16; idx += 256) {
    int m = idx >> 4, i = idx & 15;
    ks[m][i] = base[(size_t)m * 1152 + 192 + h * 16 + i];
  }
  for (int idx = tid; idx < Mn * 32; idx += 256) {
    int m = idx >> 5, e2 = idx & 31;
    vs[m][e2] = base[(size_t)m * 1152 + 384 + h * 64 + E0 + e2];
  }
  for (int idx = tid; idx < 32 * 16; idx += 256) {
    int t = idx >> 4, i = idx & 15;
    qst[t][i] = base[(size_t)(t0 + t) * 1152 + h * 16 + i];
  }
  __syncthreads();
  for (int idx = tid; idx < 32 * CH; idx += 256) {
    const int t = idx >> 7, m = idx & 127;
    if (m < Mn) {
      float s = 0.0f;
#pragma unroll
      for (int i = 0; i < 16; i++) s += qst[t][i] * ks[m][i];
      a_s[t][m] = (m <= t0 + t) ? fmaf(s, fmaf(s, 0.03125f, 0.25f), 1.0f) : 0.0f;
    }
  }
  __syncthreads();
  if (tid < 32) {
    float dsum = 0.0f;
    for (int m = 0; m < Mn; m++) dsum += a_s[tid][m];
    zl[tid] = 1.0f / (dst[(size_t)bh * LL + c * CH + t0 + tid] + dsum);
  }
  __syncthreads();
  const int e4 = (tid & 7) * 4, tq = tid >> 3;
  float ac[4] = {0.0f, 0.0f, 0.0f, 0.0f};
  for (int m = 0; m < Mn; m++) {
    float v4[4];
    *(float4*)v4 = *(const float4*)&vs[m][e4];
    const float a = a_s[tq][m];
#pragma unroll
    for (int j = 0; j < 4; j++) ac[j] += a * v4[j];
  }
  const float z = zl[tq];
  float* op = att + (size_t)(b * LL + c * CH + t0 + tq) * DM + h * 64 + E0 + e4;
  float4 y = *(const float4*)op;
  float4 w;
  w.x = (y.x + ac[0]) * z;
  w.y = (y.y + ac[1]) * z;
  w.z = (y.z + ac[2]) * z;
  w.w = (y.w + ac[3]) * z;
  *(float4*)op = w;
}

extern "C" void kernel_launch(void* const* d_in, const int* in_sizes, int n_in,
                              void* d_out, int out_size, void* d_ws, size_t ws_size,
                              hipStream_t stream) {
  const float* hs = (const float*)d_in[0];
  const float* Wq = (const float*)d_in[1];
  const float* Wk = (const float*)d_in[2];
  const float* Wv = (const float*)d_in[3];
  const float* Wo = (const float*)d_in[4];
  float* out = (float*)d_out;
  char* ws = (char*)d_ws;
  float* qkv = (float*)(ws);                     // 4096*1152*4 = 18874368
  float* att = (float*)(ws + 18874368);          // 4096*768*4  = 12582912
  float* csS = (float*)(ws + 31457280);          // 384*273*64*4 = 26836992
  float* csk = (float*)(ws + 58294272);          // 384*273*4   = 419328
  float* dst = (float*)(ws + 58713600);          // 24*2048*4   = 196608
  const dim3 thr(256);
  // Fused QKV projection: cols 0..191 q (Wq), 192..383 k (Wk), 384..1151 v (Wv)
  gemm128<<<dim3(9, 32), thr, 0, stream>>>(hs, Wq, Wk, Wv, 192, 384, qkv, 1152);
  chunk_sum_kernel<<<NBLK, thr, 0, stream>>>(qkv, csS, csk);
  {
    const int tot = NBH * DEXP * 64 + NBH * DEXP;
    prefix_kernel<<<(tot + 255) / 256, thr, 0, stream>>>(csS, csk);
  }
  state_kernel<<<dim3(NBLK, 4), thr, 0, stream>>>(qkv, csS, csk, att, dst);
  intra_kernel<<<dim3(NBLK, 4, 2), thr, 0, stream>>>(qkv, dst, att);
  gemm128<<<dim3(6, 32), thr, 0, stream>>>(att, Wo, Wo, Wo, 0, 0, out, DM);
}

// Round 3
// 345.225 us; speedup vs baseline: 1.4901x; 1.2637x over previous
//
#include <hip/hip_runtime.h>

typedef unsigned short ushortT;
typedef __bf16 bf16x8 __attribute__((ext_vector_type(8)));
typedef float f32x4 __attribute__((ext_vector_type(4)));

// Problem constants
#define BB   2
#define LL   2048
#define DM   768
#define HH   12
#define FT   16
#define HD   64
#define DEXP 273      // 1 + 16 + 256
#define CH   128      // chunk length
#define NC   16       // chunks per sequence (LL/CH)
#define NBH  24       // BB*HH
#define NBLK 384      // NBH*NC
#define C2f  0.17677669529663687f   // 1/(4*sqrt(2))
#define K2   2304     // 3*768 split-bf16 K
#define LDSS 40       // padded LDS row stride (bf16) -> 2-way conflicts only

// ---------------- split helpers ----------------
__device__ __forceinline__ void split_bf16(float x, ushortT& hi, ushortT& lo) {
  unsigned b = __float_as_uint(x);
  unsigned r = b + 0x7FFFu + ((b >> 16) & 1u);  // RNE to bf16
  hi = (ushortT)(r >> 16);
  float hf = __uint_as_float((unsigned)hi << 16);
  lo = (ushortT)(__float_as_uint(x - hf) >> 16);  // truncate
}

// X [M][768] f32 -> Xh [M][2304] bf16 = [hi | hi | lo]
__global__ __launch_bounds__(256) void pack_a(const float* __restrict__ X,
                                              ushortT* __restrict__ Xh,
                                              int total4) {
  int g = blockIdx.x * 256 + threadIdx.x;
  if (g >= total4) return;
  int m = g / 192, k4 = (g % 192) * 4;
  float4 v = *(const float4*)(X + (size_t)m * 768 + k4);
  ushortT h[4], l[4];
  split_bf16(v.x, h[0], l[0]);
  split_bf16(v.y, h[1], l[1]);
  split_bf16(v.z, h[2], l[2]);
  split_bf16(v.w, h[3], l[3]);
  ushortT* p = Xh + (size_t)m * K2 + k4;
  *(ushort4*)p = *(ushort4*)h;
  *(ushort4*)(p + 768) = *(ushort4*)h;
  *(ushort4*)(p + 1536) = *(ushort4*)l;
}

// W rows (selected from W0/W1/W2) -> Wh [N][2304] bf16 = [hi | lo | hi]
__global__ __launch_bounds__(256) void pack_w(const float* __restrict__ W0,
                                              const float* __restrict__ W1,
                                              const float* __restrict__ W2,
                                              int n1, int n2,
                                              ushortT* __restrict__ Wh,
                                              int total4) {
  int g = blockIdx.x * 256 + threadIdx.x;
  if (g >= total4) return;
  int n = g / 192, k4 = (g % 192) * 4;
  const float* src = (n < n1 ? W0 + (size_t)n * 768
                    : n < n2 ? W1 + (size_t)(n - n1) * 768
                             : W2 + (size_t)(n - n2) * 768);
  float4 v = *(const float4*)(src + k4);
  ushortT h[4], l[4];
  split_bf16(v.x, h[0], l[0]);
  split_bf16(v.y, h[1], l[1]);
  split_bf16(v.z, h[2], l[2]);
  split_bf16(v.w, h[3], l[3]);
  ushortT* p = Wh + (size_t)n * K2 + k4;
  *(ushort4*)p = *(ushort4*)h;
  *(ushort4*)(p + 768) = *(ushort4*)l;
  *(ushort4*)(p + 1536) = *(ushort4*)h;
}

// ---------------- MFMA GEMM: Y[M][N] = Ahat[M][K2] @ Bhat[N][K2]^T ----------------
// 128x128 tile, 4 waves in 2x2, each wave 64x64 via 4x4 mfma_f32_16x16x32_bf16.
__global__ __launch_bounds__(256) void mfma_gemm(const ushortT* __restrict__ A,
                                                 const ushortT* __restrict__ B,
                                                 float* __restrict__ Y, int ldy) {
  __shared__ ushortT As[128 * LDSS];
  __shared__ ushortT Bs[128 * LDSS];
  const int bm = blockIdx.y * 128, bn = blockIdx.x * 128;
  const int tid = threadIdx.x;
  const int ar = tid >> 1, ac = (tid & 1) * 16;  // row 0..127, col half 0/16
  const ushortT* gA = A + (size_t)(bm + ar) * K2 + ac;
  const ushortT* gB = B + (size_t)(bn + ar) * K2 + ac;
  ushortT* sA = &As[ar * LDSS + ac];
  ushortT* sB = &Bs[ar * LDSS + ac];
  const int wave = tid >> 6, lane = tid & 63;
  const int wm = (wave & 1) * 64, wn = (wave >> 1) * 64;
  const int fr = lane & 15, quad = lane >> 4;
  f32x4 acc[4][4] = {};
  for (int k0 = 0; k0 < K2; k0 += 32) {
    uint4 a0 = *(const uint4*)(gA + k0);
    uint4 a1 = *(const uint4*)(gA + k0 + 8);
    uint4 b0 = *(const uint4*)(gB + k0);
    uint4 b1 = *(const uint4*)(gB + k0 + 8);
    __syncthreads();
    *(uint4*)sA = a0;
    *(uint4*)(sA + 8) = a1;
    *(uint4*)sB = b0;
    *(uint4*)(sB + 8) = b1;
    __syncthreads();
    bf16x8 af[4], bfr[4];
#pragma unroll
    for (int mi = 0; mi < 4; mi++)
      af[mi] = *(const bf16x8*)&As[(wm + mi * 16 + fr) * LDSS + quad * 8];
#pragma unroll
    for (int ni = 0; ni < 4; ni++)
      bfr[ni] = *(const bf16x8*)&Bs[(wn + ni * 16 + fr) * LDSS + quad * 8];
#pragma unroll
    for (int mi = 0; mi < 4; mi++)
#pragma unroll
      for (int ni = 0; ni < 4; ni++)
        acc[mi][ni] = __builtin_amdgcn_mfma_f32_16x16x32_bf16(
            af[mi], bfr[ni], acc[mi][ni], 0, 0, 0);
  }
  const int orow = quad * 4;
#pragma unroll
  for (int mi = 0; mi < 4; mi++)
#pragma unroll
    for (int ni = 0; ni < 4; ni++) {
      float* yp = Y + (size_t)(bm + wm + mi * 16 + orow) * ldy + bn + wn + ni * 16 + fr;
#pragma unroll
      for (int r = 0; r < 4; r++) yp[(size_t)r * ldy] = acc[mi][ni][r];
    }
}

// ---------------- K2: per-chunk state sums ----------------
template <int FG>
__device__ __forceinline__ void chunk_loop(float (&acc)[69],
                                           const float (*kk)[16],
                                           const float (*vv)[64], int e) {
  for (int m = 0; m < CH; m++) {
    float kr[16];
#pragma unroll
    for (int i = 0; i < 16; i++) kr[i] = kk[m][i];
    const float vr = vv[m][e];
    float kv[16], p[16];
#pragma unroll
    for (int i = 0; i < 16; i++) kv[i] = kr[i] * vr;
#pragma unroll
    for (int i = 0; i < 16; i++) p[i] = kr[i] * C2f;
#pragma unroll
    for (int i = 0; i < 69; i++) {
      const int f = FG + 4 * i;
      if (f >= DEXP) break;
      if (f == 0)
        acc[i] += vr;
      else if (f <= 16)
        acc[i] += 0.5f * kv[f - 1];
      else
        acc[i] += p[(f - 17) >> 4] * kv[(f - 17) & 15];
    }
  }
}

__global__ __launch_bounds__(256) void chunk_sum_kernel(
    const float* __restrict__ qkv, float* __restrict__ csS,
    float* __restrict__ csk) {
  const int blk = blockIdx.x;
  const int bh = blk >> 4, c = blk & 15;
  const int b = bh / HH, h = bh % HH;
  __shared__ float kk[CH][16];
  __shared__ float vv[CH][64];
  const float* base = qkv + (size_t)(b * LL + c * CH) * 1152;
  for (int idx = threadIdx.x; idx < CH * 16; idx += 256) {
    int m = idx >> 4, i = idx & 15;
    kk[m][i] = base[(size_t)m * 1152 + 192 + h * 16 + i];
  }
  for (int idx = threadIdx.x; idx < CH * 64; idx += 256) {
    int m = idx >> 6, e2 = idx & 63;
    vv[m][e2] = base[(size_t)m * 1152 + 384 + h * 64 + e2];
  }
  __syncthreads();
  const int e = threadIdx.x & 63, fg = threadIdx.x >> 6;
  float acc[69];
#pragma unroll
  for (int i = 0; i < 69; i++) acc[i] = 0.0f;
  switch (fg) {
    case 0: chunk_loop<0>(acc, kk, vv, e); break;
    case 1: chunk_loop<1>(acc, kk, vv, e); break;
    case 2: chunk_loop<2>(acc, kk, vv, e); break;
    default: chunk_loop<3>(acc, kk, vv, e); break;
  }
  float* S = csS + (size_t)blk * DEXP * 64;
#pragma unroll
  for (int i = 0; i < 69; i++) {
    int f = fg + 4 * i;
    if (f < DEXP) S[(size_t)f * 64 + e] = acc[i];
  }
  for (int f = threadIdx.x; f < DEXP; f += 256) {
    float s = 0.0f;
    if (f == 0) {
      s = (float)CH;
    } else if (f <= 16) {
      for (int m = 0; m < CH; m++) s += kk[m][f - 1];
      s *= 0.5f;
    } else {
      int idx = f - 17, ia = idx >> 4, ib = idx & 15;
      for (int m = 0; m < CH; m++) s += kk[m][ia] * kk[m][ib];
      s *= C2f;
    }
    csk[(size_t)blk * DEXP + f] = s;
  }
}

// ---------------- K3: across-chunk scan ----------------
__global__ __launch_bounds__(256) void prefix_kernel(float* __restrict__ csS,
                                                     float* __restrict__ csk) {
  const int gid = blockIdx.x * 256 + threadIdx.x;
  const int totS = NBH * DEXP * 64;
  if (gid < totS) {
    const int bh = gid / (DEXP * 64);
    const int idx = gid % (DEXP * 64);
    float r[NC];
    float tot = 0.0f;
#pragma unroll
    for (int c = 0; c < NC; c++) {
      r[c] = csS[(size_t)(bh * NC + c) * DEXP * 64 + idx];
      tot += r[c];
    }
    float run = 0.0f;
#pragma unroll
    for (int c = 0; c < NC; c++) {
      csS[(size_t)(bh * NC + c) * DEXP * 64 + idx] = run + tot;
      run += r[c];
    }
  } else {
    const int g2 = gid - totS;
    if (g2 < NBH * DEXP) {
      const int bh = g2 / DEXP;
      const int f = g2 % DEXP;
      float r[NC];
      float tot = 0.0f;
#pragma unroll
      for (int c = 0; c < NC; c++) {
        r[c] = csk[(size_t)(bh * NC + c) * DEXP + f];
        tot += r[c];
      }
      float run = 0.0f;
#pragma unroll
      for (int c = 0; c < NC; c++) {
        csk[(size_t)(bh * NC + c) * DEXP + f] = run + tot;
        run += r[c];
      }
    }
  }
}

// ---------------- K4a: y_state = phi(q) @ G, d_state = phi(q).gk ----------------
__global__ __launch_bounds__(256) void state_kernel(
    const float* __restrict__ qkv, const float* __restrict__ csS,
    const float* __restrict__ csk, float* __restrict__ att,
    float* __restrict__ dst) {
  const int blk = blockIdx.x, tt = blockIdx.y;
  const int bh = blk >> 4, c = blk & 15;
  const int b = bh / HH, h = bh % HH;
  const int t0 = tt * 32;
  __shared__ float qst[32][17];
  __shared__ float gk[DEXP];
  const float* base = qkv + (size_t)(b * LL + c * CH) * 1152 + h * 16;
  const int tid = threadIdx.x;
  for (int idx = tid; idx < 32 * 16; idx += 256) {
    int t = idx >> 4, i = idx & 15;
    qst[t][i] = base[(size_t)(t0 + t) * 1152 + i];
  }
  for (int f = tid; f < DEXP; f += 256) gk[f] = csk[(size_t)blk * DEXP + f];
  __syncthreads();
  const float* Gc = csS + (size_t)blk * DEXP * 64;
  const int e4 = (tid & 15) * 4, tq = tid >> 4;
  float q0[16], q1[16];
#pragma unroll
  for (int i = 0; i < 16; i++) { q0[i] = qst[tq][i]; q1[i] = qst[tq + 16][i]; }
  float ac0[4], ac1[4];
  {
    float g[4];
    *(float4*)g = *(const float4*)(Gc + e4);
#pragma unroll
    for (int j = 0; j < 4; j++) { ac0[j] = g[j]; ac1[j] = g[j]; }
  }
#pragma unroll
  for (int i2 = 0; i2 < 16; i2++) {
    float g[4];
    *(float4*)g = *(const float4*)(Gc + (size_t)(1 + i2) * 64 + e4);
    const float qa = q0[i2] * 0.5f, qb = q1[i2] * 0.5f;
#pragma unroll
    for (int j = 0; j < 4; j++) { ac0[j] += qa * g[j]; ac1[j] += qb * g[j]; }
  }
  for (int i2 = 0; i2 < 16; i2++) {
    const float qa = q0[i2] * C2f, qb = q1[i2] * C2f;
    const float* Gr = Gc + (size_t)(17 + i2 * 16) * 64 + e4;
#pragma unroll
    for (int j2 = 0; j2 < 16; j2++) {
      float g[4];
      *(float4*)g = *(const float4*)(Gr + (size_t)j2 * 64);
      const float pa = qa * q0[j2], pb = qb * q1[j2];
#pragma unroll
      for (int j = 0; j < 4; j++) { ac0[j] += pa * g[j]; ac1[j] += pb * g[j]; }
    }
  }
  const size_t row0 = (size_t)(b * LL + c * CH + t0 + tq);
  float4 w0, w1;
  w0.x = ac0[0]; w0.y = ac0[1]; w0.z = ac0[2]; w0.w = ac0[3];
  w1.x = ac1[0]; w1.y = ac1[1]; w1.z = ac1[2]; w1.w = ac1[3];
  *(float4*)&att[row0 * DM + h * 64 + e4] = w0;
  *(float4*)&att[(row0 + 16) * DM + h * 64 + e4] = w1;
  if (tid < 32) {
    const int t = tid;
    float qr[16];
#pragma unroll
    for (int i = 0; i < 16; i++) qr[i] = qst[t][i];
    float d = gk[0];
#pragma unroll
    for (int i = 0; i < 16; i++) d += 0.5f * qr[i] * gk[1 + i];
#pragma unroll
    for (int i = 0; i < 16; i++) {
      const float qc = qr[i] * C2f;
#pragma unroll
      for (int j = 0; j < 16; j++) d += qc * qr[j] * gk[17 + i * 16 + j];
    }
    dst[(size_t)bh * LL + c * CH + t0 + t] = d;
  }
}

// ---------------- K4b: intra-chunk causal part + final scaling ----------------
__global__ __launch_bounds__(256) void intra_kernel(
    const float* __restrict__ qkv, const float* __restrict__ dst,
    float* __restrict__ att) {
  const int blk = blockIdx.x, tt = blockIdx.y, ez = blockIdx.z;
  const int bh = blk >> 4, c = blk & 15;
  const int b = bh / HH, h = bh % HH;
  const int t0 = tt * 32, Mn = t0 + 32;
  const int E0 = ez * 32;
  __shared__ float ks[CH][17];
  __shared__ float vs[CH][32];
  __shared__ float qst[32][17];
  __shared__ float a_s[32][129];
  __shared__ float zl[32];
  const float* base = qkv + (size_t)(b * LL + c * CH) * 1152;
  const int tid = threadIdx.x;
  for (int idx = tid; idx < Mn * 16; idx += 256) {
    int m = idx >> 4, i = idx & 15;
    ks[m][i] = base[(size_t)m * 1152 + 192 + h * 16 + i];
  }
  for (int idx = tid; idx < Mn * 32; idx += 256) {
    int m = idx >> 5, e2 = idx & 31;
    vs[m][e2] = base[(size_t)m * 1152 + 384 + h * 64 + E0 + e2];
  }
  for (int idx = tid; idx < 32 * 16; idx += 256) {
    int t = idx >> 4, i = idx & 15;
    qst[t][i] = base[(size_t)(t0 + t) * 1152 + h * 16 + i];
  }
  __syncthreads();
  for (int idx = tid; idx < 32 * CH; idx += 256) {
    const int t = idx >> 7, m = idx & 127;
    if (m < Mn) {
      float s = 0.0f;
#pragma unroll
      for (int i = 0; i < 16; i++) s += qst[t][i] * ks[m][i];
      a_s[t][m] = (m <= t0 + t) ? fmaf(s, fmaf(s, 0.03125f, 0.25f), 1.0f) : 0.0f;
    }
  }
  __syncthreads();
  if (tid < 32) {
    float dsum = 0.0f;
    for (int m = 0; m < Mn; m++) dsum += a_s[tid][m];
    zl[tid] = 1.0f / (dst[(size_t)bh * LL + c * CH + t0 + tid] + dsum);
  }
  __syncthreads();
  const int e4 = (tid & 7) * 4, tq = tid >> 3;
  float ac[4] = {0.0f, 0.0f, 0.0f, 0.0f};
  for (int m = 0; m < Mn; m++) {
    float v4[4];
    *(float4*)v4 = *(const float4*)&vs[m][e4];
    const float a = a_s[tq][m];
#pragma unroll
    for (int j = 0; j < 4; j++) ac[j] += a * v4[j];
  }
  const float z = zl[tq];
  float* op = att + (size_t)(b * LL + c * CH + t0 + tq) * DM + h * 64 + E0 + e4;
  float4 y = *(const float4*)op;
  float4 w;
  w.x = (y.x + ac[0]) * z;
  w.y = (y.y + ac[1]) * z;
  w.z = (y.z + ac[2]) * z;
  w.w = (y.w + ac[3]) * z;
  *(float4*)op = w;
}

extern "C" void kernel_launch(void* const* d_in, const int* in_sizes, int n_in,
                              void* d_out, int out_size, void* d_ws, size_t ws_size,
                              hipStream_t stream) {
  const float* hs = (const float*)d_in[0];
  const float* Wq = (const float*)d_in[1];
  const float* Wk = (const float*)d_in[2];
  const float* Wv = (const float*)d_in[3];
  const float* Wo = (const float*)d_in[4];
  float* out = (float*)d_out;
  char* ws = (char*)d_ws;
  // layout (58,910,208 bytes total, same footprint as R1):
  float* qkv = (float*)(ws);                     // [0, 18874368)
  float* att = (float*)(ws + 18874368);          // [18874368, 31457280)
  char*  regR = ws + 31457280;                   // [31457280, 58294272): Xhat -> csS -> Ahat
  float* csS = (float*)regR;
  float* csk = (float*)(ws + 58294272);          // 419328
  float* dst = (float*)(ws + 58713600);          // 196608
  ushortT* Xhat = (ushortT*)regR;                // 4096*2304*2 = 18874368 (dead before csS)
  ushortT* What = (ushortT*)att;                 // 1152*2304*2 = 5308416 (dead before att)
  ushortT* Wohat = (ushortT*)qkv;                // 768*2304*2 = 3538944 (written after intra)
  ushortT* Ahat = (ushortT*)regR;                // written after state (csS dead)
  const dim3 thr(256);
  // 1-2) pack inputs to split-bf16
  pack_a<<<3072, thr, 0, stream>>>(hs, Xhat, 4096 * 192);
  pack_w<<<864, thr, 0, stream>>>(Wq, Wk, Wv, 192, 384, What, 1152 * 192);
  // 3) fused QKV projection -> qkv fp32 [4096][1152]
  mfma_gemm<<<dim3(9, 32), thr, 0, stream>>>(Xhat, What, qkv, 1152);
  // 4-7) based linear attention
  chunk_sum_kernel<<<NBLK, thr, 0, stream>>>(qkv, csS, csk);
  {
    const int tot = NBH * DEXP * 64 + NBH * DEXP;
    prefix_kernel<<<(tot + 255) / 256, thr, 0, stream>>>(csS, csk);
  }
  state_kernel<<<dim3(NBLK, 4), thr, 0, stream>>>(qkv, csS, csk, att, dst);
  intra_kernel<<<dim3(NBLK, 4, 2), thr, 0, stream>>>(qkv, dst, att);
  // 8-9) pack for output projection (qkv and csS regions are dead now)
  pack_w<<<576, thr, 0, stream>>>(Wo, Wo, Wo, 768, 768, Wohat, 768 * 192);
  pack_a<<<3072, thr, 0, stream>>>(att, Ahat, 4096 * 192);
  // 10) output projection
  mfma_gemm<<<dim3(6, 32), thr, 0, stream>>>(Ahat, Wohat, out, DM);
}

// Round 4
// 293.641 us; speedup vs baseline: 1.7519x; 1.1757x over previous
//
#include <hip/hip_runtime.h>

typedef unsigned short ushortT;
typedef __bf16 bf16x8 __attribute__((ext_vector_type(8)));
typedef float f32x4 __attribute__((ext_vector_type(4)));

// Problem constants
#define BB   2
#define LL   2048
#define DM   768
#define HH   12
#define FT   16
#define HD   64
#define DEXP 273      // 1 + 16 + 256
#define CH   128      // chunk length
#define NC   16       // chunks per sequence (LL/CH)
#define NBH  24       // BB*HH
#define NBLK 384      // NBH*NC
#define C2f  0.17677669529663687f   // 1/(4*sqrt(2))
#define KH   768      // K per half
#define KP   1536     // packed row length: [hi(768) | lo(768)]

// ---------------- split helpers ----------------
__device__ __forceinline__ void split_bf16(float x, ushortT& hi, ushortT& lo) {
  unsigned b = __float_as_uint(x);
  unsigned r = b + 0x7FFFu + ((b >> 16) & 1u);  // RNE to bf16
  hi = (ushortT)(r >> 16);
  float hf = __uint_as_float((unsigned)hi << 16);
  lo = (ushortT)(__float_as_uint(x - hf) >> 16);  // truncate
}

// X [M][768] f32 -> Xh [M][1536] bf16 = [hi | lo]
__global__ __launch_bounds__(256) void pack_a(const float* __restrict__ X,
                                              ushortT* __restrict__ Xh,
                                              int total4) {
  int g = blockIdx.x * 256 + threadIdx.x;
  if (g >= total4) return;
  int m = g / 192, k4 = (g % 192) * 4;
  float4 v = *(const float4*)(X + (size_t)m * 768 + k4);
  ushortT h[4], l[4];
  split_bf16(v.x, h[0], l[0]);
  split_bf16(v.y, h[1], l[1]);
  split_bf16(v.z, h[2], l[2]);
  split_bf16(v.w, h[3], l[3]);
  ushortT* p = Xh + (size_t)m * KP + k4;
  *(ushort4*)p = *(ushort4*)h;
  *(ushort4*)(p + KH) = *(ushort4*)l;
}

// W rows (selected from W0/W1/W2) -> Wh [N][1536] bf16 = [hi | lo]
__global__ __launch_bounds__(256) void pack_w(const float* __restrict__ W0,
                                              const float* __restrict__ W1,
                                              const float* __restrict__ W2,
                                              int n1, int n2,
                                              ushortT* __restrict__ Wh,
                                              int total4) {
  int g = blockIdx.x * 256 + threadIdx.x;
  if (g >= total4) return;
  int n = g / 192, k4 = (g % 192) * 4;
  const float* src = (n < n1 ? W0 + (size_t)n * 768
                    : n < n2 ? W1 + (size_t)(n - n1) * 768
                             : W2 + (size_t)(n - n2) * 768);
  float4 v = *(const float4*)(src + k4);
  ushortT h[4], l[4];
  split_bf16(v.x, h[0], l[0]);
  split_bf16(v.y, h[1], l[1]);
  split_bf16(v.z, h[2], l[2]);
  split_bf16(v.w, h[3], l[3]);
  ushortT* p = Wh + (size_t)n * KP + k4;
  *(ushort4*)p = *(ushort4*)h;
  *(ushort4*)(p + KH) = *(ushort4*)l;
}

// async global->LDS, 16B per lane; lds base must be wave-uniform (lane*16 implicit)
typedef const __attribute__((address_space(1))) unsigned gq_t;
typedef __attribute__((address_space(3))) unsigned lq_t;
__device__ __forceinline__ void gload_lds16(const ushortT* g, ushortT* l) {
  __builtin_amdgcn_global_load_lds((gq_t*)g, (lq_t*)l, 16, 0, 0);
}

// ---------------- MFMA GEMM: Y[M][N] = A[M][KP] @ B[N][KP]^T (3-term split-bf16) -------
// 128x64 tile, 4 waves (2 in M x 2 in N), each wave 64x32 via 4x2 mfma_f32_16x16x32_bf16.
// Grid 1-D, XCD-swizzled: blk -> xcd = blk&7 gets M-tiles [xcd*mtp, (xcd+1)*mtp).
__global__ __launch_bounds__(256) void mfma_gemm(const ushortT* __restrict__ A,
                                                 const ushortT* __restrict__ B,
                                                 float* __restrict__ Y, int ldy,
                                                 int ntiles) {
  __shared__ ushortT sAh[128 * 32], sAl[128 * 32], sBh[64 * 32], sBl[64 * 32];
  const int blk = blockIdx.x;
  const int xcd = blk & 7, slot = blk >> 3;
  const int mtp = gridDim.x / (8 * ntiles);
  const int mt = xcd * mtp + slot / ntiles;
  const int nt = slot % ntiles;
  const int bm = mt * 128, bn = nt * 64;
  const int tid = threadIdx.x, wave = tid >> 6, lane = tid & 63;
  const int srow = lane >> 2, schk = (lane & 3) * 8;  // 16 rows x 4 chunks per iter
  const ushortT* gsrc;
  ushortT* lb;
  int iters;
  switch (wave) {
    case 0:  gsrc = A + (size_t)(bm + srow) * KP + schk;      lb = sAh; iters = 8; break;
    case 1:  gsrc = A + (size_t)(bm + srow) * KP + KH + schk; lb = sAl; iters = 8; break;
    case 2:  gsrc = B + (size_t)(bn + srow) * KP + schk;      lb = sBh; iters = 4; break;
    default: gsrc = B + (size_t)(bn + srow) * KP + KH + schk; lb = sBl; iters = 4; break;
  }
  const int wm = (wave & 1) * 64, wn = (wave >> 1) * 32;
  const int fr = lane & 15, quad = lane >> 4;
  f32x4 acc[4][2] = {};
  for (int k0 = 0; k0 < KH; k0 += 32) {
    __syncthreads();  // previous compute done before LDS overwrite
    for (int it = 0; it < iters; it++)
      gload_lds16(gsrc + k0 + (size_t)it * 16 * KP, lb + it * 512);
    __syncthreads();  // drains vmcnt (compiler-inserted before barrier)
    bf16x8 ah[4], al[4], bh2[2], bl2[2];
#pragma unroll
    for (int mi = 0; mi < 4; mi++) {
      ah[mi] = *(const bf16x8*)&sAh[(wm + mi * 16 + fr) * 32 + quad * 8];
      al[mi] = *(const bf16x8*)&sAl[(wm + mi * 16 + fr) * 32 + quad * 8];
    }
#pragma unroll
    for (int ni = 0; ni < 2; ni++) {
      bh2[ni] = *(const bf16x8*)&sBh[(wn + ni * 16 + fr) * 32 + quad * 8];
      bl2[ni] = *(const bf16x8*)&sBl[(wn + ni * 16 + fr) * 32 + quad * 8];
    }
#pragma unroll
    for (int mi = 0; mi < 4; mi++)
#pragma unroll
      for (int ni = 0; ni < 2; ni++) {
        acc[mi][ni] = __builtin_amdgcn_mfma_f32_16x16x32_bf16(ah[mi], bh2[ni], acc[mi][ni], 0, 0, 0);
        acc[mi][ni] = __builtin_amdgcn_mfma_f32_16x16x32_bf16(ah[mi], bl2[ni], acc[mi][ni], 0, 0, 0);
        acc[mi][ni] = __builtin_amdgcn_mfma_f32_16x16x32_bf16(al[mi], bh2[ni], acc[mi][ni], 0, 0, 0);
      }
  }
  const int orow = quad * 4;
#pragma unroll
  for (int mi = 0; mi < 4; mi++)
#pragma unroll
    for (int ni = 0; ni < 2; ni++) {
      float* yp = Y + (size_t)(bm + wm + mi * 16 + orow) * ldy + bn + wn + ni * 16 + fr;
#pragma unroll
      for (int r = 0; r < 4; r++) yp[(size_t)r * ldy] = acc[mi][ni][r];
    }
}

// ---------------- K2: per-chunk state sums (unchanged) ----------------
template <int FG>
__device__ __forceinline__ void chunk_loop(float (&acc)[69],
                                           const float (*kk)[16],
                                           const float (*vv)[64], int e) {
  for (int m = 0; m < CH; m++) {
    float kr[16];
#pragma unroll
    for (int i = 0; i < 16; i++) kr[i] = kk[m][i];
    const float vr = vv[m][e];
    float kv[16], p[16];
#pragma unroll
    for (int i = 0; i < 16; i++) kv[i] = kr[i] * vr;
#pragma unroll
    for (int i = 0; i < 16; i++) p[i] = kr[i] * C2f;
#pragma unroll
    for (int i = 0; i < 69; i++) {
      const int f = FG + 4 * i;
      if (f >= DEXP) break;
      if (f == 0)
        acc[i] += vr;
      else if (f <= 16)
        acc[i] += 0.5f * kv[f - 1];
      else
        acc[i] += p[(f - 17) >> 4] * kv[(f - 17) & 15];
    }
  }
}

__global__ __launch_bounds__(256) void chunk_sum_kernel(
    const float* __restrict__ qkv, float* __restrict__ csS,
    float* __restrict__ csk) {
  const int blk = blockIdx.x;
  const int bh = blk >> 4, c = blk & 15;
  const int b = bh / HH, h = bh % HH;
  __shared__ float kk[CH][16];
  __shared__ float vv[CH][64];
  const float* base = qkv + (size_t)(b * LL + c * CH) * 1152;
  for (int idx = threadIdx.x; idx < CH * 16; idx += 256) {
    int m = idx >> 4, i = idx & 15;
    kk[m][i] = base[(size_t)m * 1152 + 192 + h * 16 + i];
  }
  for (int idx = threadIdx.x; idx < CH * 64; idx += 256) {
    int m = idx >> 6, e2 = idx & 63;
    vv[m][e2] = base[(size_t)m * 1152 + 384 + h * 64 + e2];
  }
  __syncthreads();
  const int e = threadIdx.x & 63, fg = threadIdx.x >> 6;
  float acc[69];
#pragma unroll
  for (int i = 0; i < 69; i++) acc[i] = 0.0f;
  switch (fg) {
    case 0: chunk_loop<0>(acc, kk, vv, e); break;
    case 1: chunk_loop<1>(acc, kk, vv, e); break;
    case 2: chunk_loop<2>(acc, kk, vv, e); break;
    default: chunk_loop<3>(acc, kk, vv, e); break;
  }
  float* S = csS + (size_t)blk * DEXP * 64;
#pragma unroll
  for (int i = 0; i < 69; i++) {
    int f = fg + 4 * i;
    if (f < DEXP) S[(size_t)f * 64 + e] = acc[i];
  }
  for (int f = threadIdx.x; f < DEXP; f += 256) {
    float s = 0.0f;
    if (f == 0) {
      s = (float)CH;
    } else if (f <= 16) {
      for (int m = 0; m < CH; m++) s += kk[m][f - 1];
      s *= 0.5f;
    } else {
      int idx = f - 17, ia = idx >> 4, ib = idx & 15;
      for (int m = 0; m < CH; m++) s += kk[m][ia] * kk[m][ib];
      s *= C2f;
    }
    csk[(size_t)blk * DEXP + f] = s;
  }
}

// ---------------- K3: across-chunk scan ----------------
__global__ __launch_bounds__(256) void prefix_kernel(float* __restrict__ csS,
                                                     float* __restrict__ csk) {
  const int gid = blockIdx.x * 256 + threadIdx.x;
  const int totS = NBH * DEXP * 64;
  if (gid < totS) {
    const int bh = gid / (DEXP * 64);
    const int idx = gid % (DEXP * 64);
    float r[NC];
    float tot = 0.0f;
#pragma unroll
    for (int c = 0; c < NC; c++) {
      r[c] = csS[(size_t)(bh * NC + c) * DEXP * 64 + idx];
      tot += r[c];
    }
    float run = 0.0f;
#pragma unroll
    for (int c = 0; c < NC; c++) {
      csS[(size_t)(bh * NC + c) * DEXP * 64 + idx] = run + tot;
      run += r[c];
    }
  } else {
    const int g2 = gid - totS;
    if (g2 < NBH * DEXP) {
      const int bh = g2 / DEXP;
      const int f = g2 % DEXP;
      float r[NC];
      float tot = 0.0f;
#pragma unroll
      for (int c = 0; c < NC; c++) {
        r[c] = csk[(size_t)(bh * NC + c) * DEXP + f];
        tot += r[c];
      }
      float run = 0.0f;
#pragma unroll
      for (int c = 0; c < NC; c++) {
        csk[(size_t)(bh * NC + c) * DEXP + f] = run + tot;
        run += r[c];
      }
    }
  }
}

// ---------------- K4a: y_state = phi(q) @ G (full chunk per block, G read once) --------
// grid (NBLK). Thread (rg, eg): rows rg*8..rg*8+7, cols eg*4..eg*4+3.
__global__ __launch_bounds__(256) void state_kernel(
    const float* __restrict__ qkv, const float* __restrict__ csS,
    const float* __restrict__ csk, float* __restrict__ att,
    float* __restrict__ dst) {
  const int blk = blockIdx.x;
  const int bh = blk >> 4, c = blk & 15;
  const int b = bh / HH, h = bh % HH;
  __shared__ float qs[CH][17];
  __shared__ float phi_s[16][CH];
  __shared__ float Gs[16][68];
  __shared__ float gks[16];
  const float* base = qkv + (size_t)(b * LL + c * CH) * 1152 + h * 16;
  const int tid = threadIdx.x;
  for (int idx = tid; idx < CH * 16; idx += 256) {
    int t = idx >> 4, i = idx & 15;
    qs[t][i] = base[(size_t)t * 1152 + i];
  }
  const float* Gc = csS + (size_t)blk * DEXP * 64;
  const float* gkp = csk + (size_t)blk * DEXP;
  const int eg = tid & 15, e4 = eg * 4, rg = tid >> 4;
  float acc[8][4] = {};
  float dacc = 0.0f;
  __syncthreads();
  for (int s = 0; s < 18; s++) {
    const int f0 = s * 16;
    const int fn = (DEXP - f0 < 16) ? (DEXP - f0) : 16;
    __syncthreads();  // protect phi_s/Gs reuse
    for (int idx = tid; idx < fn * CH; idx += 256) {
      int fi = idx >> 7, t = idx & 127;
      int f = f0 + fi;
      float v;
      if (f == 0) v = 1.0f;
      else if (f <= 16) v = 0.5f * qs[t][f - 1];
      else { int ii = f - 17; v = C2f * qs[t][ii >> 4] * qs[t][ii & 15]; }
      phi_s[fi][t] = v;
    }
    if (tid < fn * 16) {
      int fi = tid >> 4, e = (tid & 15) * 4;
      *(float4*)&Gs[fi][e] = *(const float4*)&Gc[(size_t)(f0 + fi) * 64 + e];
    }
    if (tid < fn) gks[tid] = gkp[f0 + tid];
    __syncthreads();
    for (int fi = 0; fi < fn; fi++) {
      float g[4];
      *(float4*)g = *(const float4*)&Gs[fi][e4];
#pragma unroll
      for (int r = 0; r < 8; r++) {
        const float cf = phi_s[fi][rg * 8 + r];
#pragma unroll
        for (int j = 0; j < 4; j++) acc[r][j] += cf * g[j];
      }
    }
    if (tid < CH) {
      for (int fi = 0; fi < fn; fi++) dacc += phi_s[fi][tid] * gks[fi];
    }
  }
  const size_t rowb = (size_t)(b * LL + c * CH);
#pragma unroll
  for (int r = 0; r < 8; r++) {
    float4 w;
    w.x = acc[r][0]; w.y = acc[r][1]; w.z = acc[r][2]; w.w = acc[r][3];
    *(float4*)&att[(rowb + rg * 8 + r) * DM + h * 64 + e4] = w;
  }
  if (tid < CH) dst[(size_t)bh * LL + c * CH + tid] = dacc;
}

// ---------------- K4b: intra-chunk causal part + final scaling (full 64-wide) ----------
// grid (NBLK, 4). 32-row tile, all 64 V columns in one block.
__global__ __launch_bounds__(256) void intra_kernel(
    const float* __restrict__ qkv, const float* __restrict__ dst,
    float* __restrict__ att) {
  const int blk = blockIdx.x, tt = blockIdx.y;
  const int bh = blk >> 4, c = blk & 15;
  const int b = bh / HH, h = bh % HH;
  const int t0 = tt * 32, Mn = t0 + 32;
  __shared__ float ks[CH][17];
  __shared__ float vs[CH][68];
  __shared__ float qst[32][17];
  __shared__ float a_s[32][132];
  __shared__ float zl[32];
  const float* base = qkv + (size_t)(b * LL + c * CH) * 1152;
  const int tid = threadIdx.x;
  for (int idx = tid; idx < Mn * 16; idx += 256) {
    int m = idx >> 4, i = idx & 15;
    ks[m][i] = base[(size_t)m * 1152 + 192 + h * 16 + i];
  }
  for (int idx = tid; idx < Mn * 16; idx += 256) {
    int m = idx >> 4, e4g = (idx & 15) * 4;
    *(float4*)&vs[m][e4g] = *(const float4*)&base[(size_t)m * 1152 + 384 + h * 64 + e4g];
  }
  for (int idx = tid; idx < 32 * 16; idx += 256) {
    int t = idx >> 4, i = idx & 15;
    qst[t][i] = base[(size_t)(t0 + t) * 1152 + h * 16 + i];
  }
  __syncthreads();
  for (int idx = tid; idx < 32 * CH; idx += 256) {
    const int t = idx >> 7, m = idx & 127;
    if (m < Mn) {
      float s = 0.0f;
#pragma unroll
      for (int i = 0; i < 16; i++) s += qst[t][i] * ks[m][i];
      a_s[t][m] = (m <= t0 + t) ? fmaf(s, fmaf(s, 0.03125f, 0.25f), 1.0f) : 0.0f;
    }
  }
  __syncthreads();
  if (tid < 32) {
    float dsum = 0.0f;
    for (int m = 0; m < Mn; m++) dsum += a_s[tid][m];
    zl[tid] = 1.0f / (dst[(size_t)bh * LL + c * CH + t0 + tid] + dsum);
  }
  __syncthreads();
  const int e4 = (tid & 15) * 4, tq = tid >> 4;  // rows t0+tq, t0+tq+16
  float ac0[4] = {0, 0, 0, 0}, ac1[4] = {0, 0, 0, 0};
  for (int m = 0; m < Mn; m++) {
    float v4[4];
    *(float4*)v4 = *(const float4*)&vs[m][e4];
    const float a0 = a_s[tq][m], a1 = a_s[tq + 16][m];
#pragma unroll
    for (int j = 0; j < 4; j++) { ac0[j] += a0 * v4[j]; ac1[j] += a1 * v4[j]; }
  }
  const float z0 = zl[tq], z1 = zl[tq + 16];
  float* o0 = att + (size_t)(b * LL + c * CH + t0 + tq) * DM + h * 64 + e4;
  float* o1 = att + (size_t)(b * LL + c * CH + t0 + tq + 16) * DM + h * 64 + e4;
  float4 y0 = *(const float4*)o0;
  float4 y1 = *(const float4*)o1;
  float4 w0, w1;
  w0.x = (y0.x + ac0[0]) * z0; w0.y = (y0.y + ac0[1]) * z0;
  w0.z = (y0.z + ac0[2]) * z0; w0.w = (y0.w + ac0[3]) * z0;
  w1.x = (y1.x + ac1[0]) * z1; w1.y = (y1.y + ac1[1]) * z1;
  w1.z = (y1.z + ac1[2]) * z1; w1.w = (y1.w + ac1[3]) * z1;
  *(float4*)o0 = w0;
  *(float4*)o1 = w1;
}

extern "C" void kernel_launch(void* const* d_in, const int* in_sizes, int n_in,
                              void* d_out, int out_size, void* d_ws, size_t ws_size,
                              hipStream_t stream) {
  const float* hs = (const float*)d_in[0];
  const float* Wq = (const float*)d_in[1];
  const float* Wk = (const float*)d_in[2];
  const float* Wv = (const float*)d_in[3];
  const float* Wo = (const float*)d_in[4];
  float* out = (float*)d_out;
  char* ws = (char*)d_ws;
  // layout (58,910,208 bytes, same footprint as R2/R3):
  float* qkv = (float*)(ws);                     // [0, 18874368)
  float* att = (float*)(ws + 18874368);          // [18874368, 31457280)
  char*  regR = ws + 31457280;                   // [31457280, 58294272): Xhat -> csS -> Ahat
  float* csS = (float*)regR;
  float* csk = (float*)(ws + 58294272);          // 419328
  float* dst = (float*)(ws + 58713600);          // 196608
  ushortT* Xhat = (ushortT*)regR;                // 4096*1536*2 = 12.6 MB (dead before csS)
  ushortT* What = (ushortT*)att;                 // 1152*1536*2 = 3.5 MB (dead before att)
  ushortT* Wohat = (ushortT*)qkv;                // 768*1536*2 (written after intra)
  ushortT* Ahat = (ushortT*)regR;                // written after state+intra (csS dead)
  const dim3 thr(256);
  // 1-2) pack inputs to [hi|lo] split-bf16
  pack_a<<<3072, thr, 0, stream>>>(hs, Xhat, 4096 * 192);
  pack_w<<<864, thr, 0, stream>>>(Wq, Wk, Wv, 192, 384, What, 1152 * 192);
  // 3) fused QKV projection -> qkv fp32 [4096][1152]; 32 M-tiles x 18 N-tiles, XCD-swizzled
  mfma_gemm<<<576, thr, 0, stream>>>(Xhat, What, qkv, 1152, 18);
  // 4-7) based linear attention
  chunk_sum_kernel<<<NBLK, thr, 0, stream>>>(qkv, csS, csk);
  {
    const int tot = NBH * DEXP * 64 + NBH * DEXP;
    prefix_kernel<<<(tot + 255) / 256, thr, 0, stream>>>(csS, csk);
  }
  state_kernel<<<NBLK, thr, 0, stream>>>(qkv, csS, csk, att, dst);
  intra_kernel<<<dim3(NBLK, 4), thr, 0, stream>>>(qkv, dst, att);
  // 8-9) pack for output projection (qkv and csS regions dead now)
  pack_w<<<576, thr, 0, stream>>>(Wo, Wo, Wo, 768, 768, Wohat, 768 * 192);
  pack_a<<<3072, thr, 0, stream>>>(att, Ahat, 4096 * 192);
  // 10) output projection: 32 M-tiles x 12 N-tiles
  mfma_gemm<<<384, thr, 0, stream>>>(Ahat, Wohat, out, DM, 12);
}